// Round 7
// baseline (2942.829 us; speedup 1.0000x reference)
//
#include <hip/hip_runtime.h>
#include <hip/hip_fp16.h>
#include <math.h>

#define NN 200000
#define NE 6400000
#define DIM 128
#define NG 2048
#define NC 10
#define BN_EPS 1e-5f
#define NS 4                 // src stripes (by src>>16): <=16.8MB fp16 each
#define NN4 (NN * NS)        // per-(node,stripe) list count
// padded CSR upper bound: NE + NN4*7
#define NE_PAD 12200000

__device__ __forceinline__ float elu_f(float x) { return x > 0.f ? x : (expf(x) - 1.f); }

__device__ __forceinline__ unsigned enc_f(float f) {
    unsigned u = __float_as_uint(f);
    return (u & 0x80000000u) ? ~u : (u | 0x80000000u);
}
__device__ __forceinline__ float dec_f(unsigned k) {
    unsigned u = (k & 0x80000000u) ? (k & 0x7FFFFFFFu) : ~k;
    return __uint_as_float(u);
}

// ---------------- fp32 -> fp16 feature conversion ----------------

__global__ void to_half_kernel(const float* __restrict__ in, __half* __restrict__ out, int n2) {
    int i = blockIdx.x * blockDim.x + threadIdx.x;
    int stride = gridDim.x * blockDim.x;
    const float2* in2 = reinterpret_cast<const float2*>(in);
    __half2* out2 = reinterpret_cast<__half2*>(out);
    for (; i < n2; i += stride) out2[i] = __float22half2_rn(in2[i]);
}

// ---------------- CSR build: per-(node,stripe) lists, padded to mult of 8 ----------------

__global__ void hist_kernel(const int* __restrict__ src, const int* __restrict__ dst,
                            int* __restrict__ counts) {
    int i = blockIdx.x * blockDim.x + threadIdx.x;
    int stride = gridDim.x * blockDim.x;
    for (; i < NE; i += stride) {
        int s = src[i] >> 16;  // stripe 0..3
        atomicAdd(&counts[dst[i] * NS + s], 1);
    }
}

__global__ __launch_bounds__(1024) void scan_block_kernel(const int* __restrict__ counts,
                                                          int* __restrict__ offs,
                                                          int* __restrict__ bsum) {
    __shared__ int sdat[1024];
    const int t = threadIdx.x;
    const int i = blockIdx.x * 1024 + t;
    int v = (i < NN4) ? ((counts[i] + 7) & ~7) : 0;  // pad each sublist to mult of 8
    sdat[t] = v;
    __syncthreads();
    for (int o = 1; o < 1024; o <<= 1) {
        int a = (t >= o) ? sdat[t - o] : 0;
        __syncthreads();
        sdat[t] += a;
        __syncthreads();
    }
    if (i < NN4) offs[i] = sdat[t] - v;  // exclusive within block
    if (t == 1023) bsum[blockIdx.x] = sdat[t];
}

__global__ void scan_bsum_kernel(const int* __restrict__ bsum, int* __restrict__ bscan,
                                 int nb, int* __restrict__ offs) {
    if (threadIdx.x == 0 && blockIdx.x == 0) {
        int acc = 0;
        for (int b = 0; b < nb; ++b) { bscan[b] = acc; acc += bsum[b]; }
        offs[NN4] = acc;  // total padded edge count
    }
}

__global__ void add_bscan_kernel(int* __restrict__ offs, const int* __restrict__ bscan,
                                 int* __restrict__ cursor) {
    int i = blockIdx.x * blockDim.x + threadIdx.x;
    if (i < NN4) {
        int o = offs[i] + bscan[i >> 10];
        offs[i] = o;
        cursor[i] = o;
    }
}

// init padded csr with the dummy zero-row index NN (streaming nt stores)
__global__ void csr_init_kernel(int* __restrict__ csr) {
    int i = blockIdx.x * blockDim.x + threadIdx.x;
    int stride = gridDim.x * blockDim.x;
    for (; i < NE_PAD; i += stride) __builtin_nontemporal_store(NN, &csr[i]);
}

__global__ void fill_kernel(const int* __restrict__ src, const int* __restrict__ dst,
                            int* __restrict__ cursor, int* __restrict__ csr) {
    int i = blockIdx.x * blockDim.x + threadIdx.x;
    int stride = gridDim.x * blockDim.x;
    for (; i < NE; i += stride) {
        int sv = src[i];
        int p = atomicAdd(&cursor[dst[i] * NS + (sv >> 16)], 1);
        csr[p] = sv;
    }
}

// ---------------- BN fold ----------------

__global__ void fold_kernel(const float* __restrict__ W1, const float* __restrict__ b1,
                            const float* __restrict__ gamma, const float* __restrict__ beta,
                            const float* __restrict__ rm, const float* __restrict__ rv,
                            float* __restrict__ W1f, float* __restrict__ b1f) {
    int idx = blockIdx.x * blockDim.x + threadIdx.x;
    if (idx < DIM * DIM) {
        int c = idx & (DIM - 1);
        float sc = rsqrtf(rv[c] + BN_EPS) * gamma[c];
        W1f[idx] = W1[idx] * sc;
        if (idx < DIM) {
            float s2 = rsqrtf(rv[idx] + BN_EPS) * gamma[idx];
            b1f[idx] = (b1[idx] - rm[idx]) * s2 + beta[idx];
        }
    }
}

// ---------------- fused GIN layer: stripe-blocked gather + MLP (+optional pool) ----------------

#define TPAD 130  // half stride: 65 dwords -> bank-conflict-free column access

__device__ __forceinline__ void gemm_tile(const __half (*tile)[TPAD], int node, int c0,
                                          const float* __restrict__ W, const float* __restrict__ b,
                                          float r[32]) {
#pragma unroll
    for (int c = 0; c < 32; ++c) r[c] = b[c0 + c];
    const float4* W4 = reinterpret_cast<const float4*>(W);
    for (int k = 0; k < DIM; ++k) {
        const float a = __half2float(tile[node][k]);
        const float4* wr = W4 + k * (DIM / 4) + (c0 >> 2);
#pragma unroll
        for (int q = 0; q < 8; ++q) {
            float4 w = wr[q];
            r[q * 4 + 0] += a * w.x;
            r[q * 4 + 1] += a * w.y;
            r[q * 4 + 2] += a * w.z;
            r[q * 4 + 3] += a * w.w;
        }
    }
}

__device__ __forceinline__ void acc_row(const int4& raw, float* a) {
    float2 f;
    f = __half22float2(*reinterpret_cast<const __half2*>(&raw.x)); a[0] += f.x; a[1] += f.y;
    f = __half22float2(*reinterpret_cast<const __half2*>(&raw.y)); a[2] += f.x; a[3] += f.y;
    f = __half22float2(*reinterpret_cast<const __half2*>(&raw.z)); a[4] += f.x; a[5] += f.y;
    f = __half22float2(*reinterpret_cast<const __half2*>(&raw.w)); a[6] += f.x; a[7] += f.y;
}

template <int POOL>
__global__ __launch_bounds__(256) void gin_layer_kernel(
    const __half* __restrict__ fin, const int* __restrict__ offs2, const int* __restrict__ csr,
    const float* __restrict__ W1f, const float* __restrict__ b1f,
    const float* __restrict__ W2, const float* __restrict__ b2,
    __half* __restrict__ hout, unsigned int* __restrict__ gkey, const int* __restrict__ batch) {
    __shared__ __half accT[64][TPAD];  // 16.6 KB
    __shared__ int batch_s[64];

    const int base = blockIdx.x * 64;
    const int t = threadIdx.x;
    const int lane = t & 63;
    const int wave = t >> 6;

    if (POOL && t < 64) batch_s[t] = batch[base + t];

    const char* finb = reinterpret_cast<const char*>(fin);
    const int g = lane >> 4;            // group 0..3: one node's walk per group
    const int sub = lane & 15;          // 16 B slice within the 256 B feature row
    const size_t boff = (size_t)sub << 4;
    const int k7 = lane & 7;
    const int gl = lane & 48;           // group's base lane for shfl

    float a[4][8];

    // ---- init acc with own rows (replaces self-edge) ----
#pragma unroll
    for (int q = 0; q < 4; ++q) {
        const int n = base + wave * 16 + q * 4 + g;
#pragma unroll
        for (int k = 0; k < 8; ++k) a[q][k] = 0.f;
        int4 own = *reinterpret_cast<const int4*>(finb + ((size_t)n << 8) + boff);
        acc_row(own, a[q]);
    }

    // ---- stripe-outer aggregation: all resident blocks sweep the same ~13MB window ----
    for (int s = 0; s < NS; ++s) {
#pragma unroll
        for (int q = 0; q < 4; ++q) {
            const int n = base + wave * 16 + q * 4 + g;
            const int i4 = n * NS + s;
            const int e0 = offs2[i4];
            const int len = offs2[i4 + 1] - e0;   // mult of 8 (may be 0); group-uniform
            int idxv = (k7 < len) ? csr[e0 + k7] : NN;
            for (int kb = 0; kb < len; kb += 8) { // 4-way group divergence, exec-masked
                int idxn = NN;
                if (kb + 8 < len) idxn = csr[e0 + kb + 8 + k7];
                int s0 = __shfl(idxv, gl + 0);
                int s1 = __shfl(idxv, gl + 1);
                int s2 = __shfl(idxv, gl + 2);
                int s3 = __shfl(idxv, gl + 3);
                int s4 = __shfl(idxv, gl + 4);
                int s5 = __shfl(idxv, gl + 5);
                int s6 = __shfl(idxv, gl + 6);
                int s7 = __shfl(idxv, gl + 7);
                int4 r0 = *reinterpret_cast<const int4*>(finb + ((size_t)s0 << 8) + boff);
                int4 r1 = *reinterpret_cast<const int4*>(finb + ((size_t)s1 << 8) + boff);
                int4 r2 = *reinterpret_cast<const int4*>(finb + ((size_t)s2 << 8) + boff);
                int4 r3 = *reinterpret_cast<const int4*>(finb + ((size_t)s3 << 8) + boff);
                int4 r4 = *reinterpret_cast<const int4*>(finb + ((size_t)s4 << 8) + boff);
                int4 r5 = *reinterpret_cast<const int4*>(finb + ((size_t)s5 << 8) + boff);
                int4 r6 = *reinterpret_cast<const int4*>(finb + ((size_t)s6 << 8) + boff);
                int4 r7 = *reinterpret_cast<const int4*>(finb + ((size_t)s7 << 8) + boff);
                acc_row(r0, a[q]);
                acc_row(r1, a[q]);
                acc_row(r2, a[q]);
                acc_row(r3, a[q]);
                acc_row(r4, a[q]);
                acc_row(r5, a[q]);
                acc_row(r6, a[q]);
                acc_row(r7, a[q]);
                idxv = idxn;
            }
        }
    }

    // ---- write accumulators to tile: lane (g,sub) holds feats sub*8..+7 of its node ----
#pragma unroll
    for (int q = 0; q < 4; ++q) {
        const int row = wave * 16 + q * 4 + g;
        const int c = sub * 8;
        float2 f;
        f.x = a[q][0]; f.y = a[q][1];
        *reinterpret_cast<__half2*>(&accT[row][c + 0]) = __float22half2_rn(f);
        f.x = a[q][2]; f.y = a[q][3];
        *reinterpret_cast<__half2*>(&accT[row][c + 2]) = __float22half2_rn(f);
        f.x = a[q][4]; f.y = a[q][5];
        *reinterpret_cast<__half2*>(&accT[row][c + 4]) = __float22half2_rn(f);
        f.x = a[q][6]; f.y = a[q][7];
        *reinterpret_cast<__half2*>(&accT[row][c + 6]) = __float22half2_rn(f);
    }
    __syncthreads();

    const int node = t & 63;
    const int c0 = (t >> 6) * 32;
    float r[32];

    // ---- GEMM1 (BN folded) + ELU ----
    gemm_tile(accT, node, c0, W1f, b1f, r);
#pragma unroll
    for (int c = 0; c < 32; ++c) r[c] = elu_f(r[c]);
    __syncthreads();
#pragma unroll
    for (int c = 0; c < 32; ++c) accT[node][c0 + c] = __float2half(r[c]);
    __syncthreads();

    // ---- GEMM2 + ELU ----
    gemm_tile(accT, node, c0, W2, b2, r);
#pragma unroll
    for (int c = 0; c < 32; ++c) r[c] = elu_f(r[c]);
    __syncthreads();
#pragma unroll
    for (int c = 0; c < 32; ++c) accT[node][c0 + c] = __float2half(r[c]);
    __syncthreads();

    if (!POOL) {
        __half2* hout2 = reinterpret_cast<__half2*>(hout);
        for (int idx = t; idx < 64 * 64; idx += 256) {
            int n = idx >> 6, c2 = idx & 63;
            hout2[(size_t)(base + n) * 64 + c2] =
                *reinterpret_cast<const __half2*>(&accT[n][2 * c2]);
        }
    } else {
        if (t < DIM) {
            const int col = t;
            const int g0 = batch_s[0], g1 = batch_s[63];
            for (int gg = g0; gg <= g1; ++gg) {
                float m = -INFINITY;
                bool any = false;
                for (int i = 0; i < 64; ++i) {
                    if (batch_s[i] == gg) { m = fmaxf(m, __half2float(accT[i][col])); any = true; }
                }
                if (any) atomicMax(&gkey[(size_t)gg * DIM + col], enc_f(m));
            }
        }
    }
}

// ---------------- head ----------------

__global__ __launch_bounds__(128) void head_kernel(const unsigned int* __restrict__ gkey,
                                                   const float* __restrict__ l1W,
                                                   const float* __restrict__ l1b,
                                                   const float* __restrict__ l2W,
                                                   const float* __restrict__ l2b,
                                                   float* __restrict__ out) {
    __shared__ float gv[DIM];
    __shared__ float y1[DIM];
    __shared__ float lg[NC];
    const int g = blockIdx.x;
    const int t = threadIdx.x;
    gv[t] = dec_f(gkey[(size_t)g * DIM + t]);
    __syncthreads();
    float s = l1b[t];
    for (int k = 0; k < DIM; ++k) s += gv[k] * l1W[k * DIM + t];
    y1[t] = elu_f(s);
    __syncthreads();
    if (t < NC) {
        float s2 = l2b[t];
        for (int k = 0; k < DIM; ++k) s2 += y1[k] * l2W[k * NC + t];
        lg[t] = s2;
    }
    __syncthreads();
    if (t == 0) {
        float m = -INFINITY;
        for (int j = 0; j < NC; ++j) m = fmaxf(m, lg[j]);
        float e[NC];
        float sum = 0.f;
        for (int j = 0; j < NC; ++j) { e[j] = expf(lg[j] - m); sum += e[j]; }
        float inv = 1.f / sum;
        for (int j = 0; j < NC; ++j) out[(size_t)g * NC + j] = e[j] * inv;
    }
}

// ---------------- launch ----------------

extern "C" void kernel_launch(void* const* d_in, const int* in_sizes, int n_in,
                              void* d_out, int out_size, void* d_ws, size_t ws_size,
                              hipStream_t stream) {
    (void)in_sizes; (void)n_in; (void)out_size; (void)ws_size;
    const float* x     = (const float*)d_in[0];
    const int*   edge  = (const int*)d_in[1];
    const int*   batch = (const int*)d_in[2];
    const float* c1_W1 = (const float*)d_in[3];
    const float* c1_b1 = (const float*)d_in[4];
    const float* c1_g  = (const float*)d_in[5];
    const float* c1_be = (const float*)d_in[6];
    const float* c1_rm = (const float*)d_in[7];
    const float* c1_rv = (const float*)d_in[8];
    const float* c1_W2 = (const float*)d_in[9];
    const float* c1_b2 = (const float*)d_in[10];
    const float* c2_W1 = (const float*)d_in[11];
    const float* c2_b1 = (const float*)d_in[12];
    const float* c2_g  = (const float*)d_in[13];
    const float* c2_be = (const float*)d_in[14];
    const float* c2_rm = (const float*)d_in[15];
    const float* c2_rv = (const float*)d_in[16];
    const float* c2_W2 = (const float*)d_in[17];
    const float* c2_b2 = (const float*)d_in[18];
    const float* l1_W  = (const float*)d_in[19];
    const float* l1_b  = (const float*)d_in[20];
    const float* l2_W  = (const float*)d_in[21];
    const float* l2_b  = (const float*)d_in[22];
    float* out = (float*)d_out;

    char* wsb = (char*)d_ws;
    size_t off = 0;
    auto take = [&](size_t bytes) -> char* {
        char* p = wsb + off;
        off += (bytes + 255) & ~(size_t)255;
        return p;
    };
    int* counts2   = (int*)take((size_t)NN4 * 4);
    int* offs2     = (int*)take((size_t)(NN4 + 1) * 4);
    int* cursor2   = (int*)take((size_t)NN4 * 4);
    int* bsum      = (int*)take(1024 * 4);
    int* bscan     = (int*)take(1024 * 4);
    int* csr       = (int*)take((size_t)NE_PAD * 4);
    __half* xh     = (__half*)take((size_t)(NN + 1) * DIM * 2);   // +1: zero pad row
    __half* h1h    = (__half*)take((size_t)(NN + 1) * DIM * 2);
    unsigned* gkey = (unsigned*)take((size_t)NG * DIM * 4);
    float* W1f_a   = (float*)take((size_t)DIM * DIM * 4);
    float* b1f_a   = (float*)take((size_t)DIM * 4);
    float* W1f_b   = (float*)take((size_t)DIM * DIM * 4);
    float* b1f_b   = (float*)take((size_t)DIM * 4);

    const int* esrc = edge;
    const int* edst = edge + NE;

    hipMemsetAsync(counts2, 0, (size_t)NN4 * 4, stream);
    hipMemsetAsync(gkey, 0, (size_t)NG * DIM * 4, stream);
    hipMemsetAsync(xh + (size_t)NN * DIM, 0, DIM * 2, stream);
    hipMemsetAsync(h1h + (size_t)NN * DIM, 0, DIM * 2, stream);

    fold_kernel<<<64, 256, 0, stream>>>(c1_W1, c1_b1, c1_g, c1_be, c1_rm, c1_rv, W1f_a, b1f_a);
    fold_kernel<<<64, 256, 0, stream>>>(c2_W1, c2_b1, c2_g, c2_be, c2_rm, c2_rv, W1f_b, b1f_b);

    to_half_kernel<<<2048, 256, 0, stream>>>(x, xh, NN * DIM / 2);

    hist_kernel<<<4096, 256, 0, stream>>>(esrc, edst, counts2);
    scan_block_kernel<<<782, 1024, 0, stream>>>(counts2, offs2, bsum);
    scan_bsum_kernel<<<1, 1, 0, stream>>>(bsum, bscan, 782, offs2);
    add_bscan_kernel<<<3125, 256, 0, stream>>>(offs2, bscan, cursor2);
    csr_init_kernel<<<4096, 256, 0, stream>>>(csr);
    fill_kernel<<<4096, 256, 0, stream>>>(esrc, edst, cursor2, csr);

    gin_layer_kernel<0><<<NN / 64, 256, 0, stream>>>(xh, offs2, csr, W1f_a, b1f_a, c1_W2, c1_b2,
                                                     h1h, nullptr, nullptr);
    gin_layer_kernel<1><<<NN / 64, 256, 0, stream>>>(h1h, offs2, csr, W1f_b, b1f_b, c2_W2, c2_b2,
                                                     nullptr, gkey, batch);

    head_kernel<<<NG, 128, 0, stream>>>(gkey, l1_W, l1_b, l2_W, l2_b, out);
}

// Round 10
// 1305.206 us; speedup vs baseline: 2.2547x; 2.2547x over previous
//
#include <hip/hip_runtime.h>
#include <hip/hip_fp16.h>
#include <math.h>

#define NN 200000
#define NE 6400000
#define DIM 128
#define NG 2048
#define NC 10
#define BN_EPS 1e-5f
// padded CSR upper bound: NE + NN*(1 self + up to 7 pad) = 8.0M
#define NE_PAD 8200000

typedef _Float16 f16x8 __attribute__((ext_vector_type(8)));
typedef float f32x4 __attribute__((ext_vector_type(4)));

__device__ __forceinline__ float elu_f(float x) { return x > 0.f ? x : (expf(x) - 1.f); }

__device__ __forceinline__ unsigned enc_f(float f) {
    unsigned u = __float_as_uint(f);
    return (u & 0x80000000u) ? ~u : (u | 0x80000000u);
}
__device__ __forceinline__ float dec_f(unsigned k) {
    unsigned u = (k & 0x80000000u) ? (k & 0x7FFFFFFFu) : ~k;
    return __uint_as_float(u);
}

// ---------------- fp32 -> fp16 feature conversion ----------------

__global__ void to_half_kernel(const float* __restrict__ in, __half* __restrict__ out, int n2) {
    int i = blockIdx.x * blockDim.x + threadIdx.x;
    int stride = gridDim.x * blockDim.x;
    const float2* in2 = reinterpret_cast<const float2*>(in);
    __half2* out2 = reinterpret_cast<__half2*>(out);
    for (; i < n2; i += stride) out2[i] = __float22half2_rn(in2[i]);
}

// ---------------- CSR build (self-edge via add_bscan, degree padded to mult of 8) ----------------

__global__ void hist_kernel(const int* __restrict__ dst, int* __restrict__ counts) {
    int i = blockIdx.x * blockDim.x + threadIdx.x;
    int stride = gridDim.x * blockDim.x;
    for (; i < NE; i += stride) atomicAdd(&counts[dst[i]], 1);
}

__global__ __launch_bounds__(1024) void scan_block_kernel(const int* __restrict__ counts,
                                                          int* __restrict__ offs,
                                                          int* __restrict__ bsum) {
    __shared__ int sdat[1024];
    const int t = threadIdx.x;
    const int i = blockIdx.x * 1024 + t;
    // +1 self edge, then pad to multiple of 8
    int v = (i < NN) ? ((counts[i] + 8) & ~7) : 0;
    sdat[t] = v;
    __syncthreads();
    for (int o = 1; o < 1024; o <<= 1) {
        int a = (t >= o) ? sdat[t - o] : 0;
        __syncthreads();
        sdat[t] += a;
        __syncthreads();
    }
    if (i < NN) offs[i] = sdat[t] - v;  // exclusive within block
    if (t == 1023) bsum[blockIdx.x] = sdat[t];
}

// parallel scan over block sums (nb <= 1024), one block
__global__ __launch_bounds__(1024) void scan_bsum_kernel(const int* __restrict__ bsum,
                                                         int* __restrict__ bscan,
                                                         int nb, int* __restrict__ offs) {
    __shared__ int s[1024];
    const int t = threadIdx.x;
    int v = (t < nb) ? bsum[t] : 0;
    s[t] = v;
    __syncthreads();
    for (int o = 1; o < 1024; o <<= 1) {
        int a = (t >= o) ? s[t - o] : 0;
        __syncthreads();
        s[t] += a;
        __syncthreads();
    }
    if (t < nb) bscan[t] = s[t] - v;
    if (nb > 0 && t == nb - 1) offs[NN] = s[t];
}

// init padded csr with the dummy zero-row index NN
__global__ void csr_init_kernel(int* __restrict__ csr) {
    int i = blockIdx.x * blockDim.x + threadIdx.x;
    int stride = gridDim.x * blockDim.x;
    for (; i < NE_PAD; i += stride) csr[i] = NN;
}

// finalize offsets, plant self-edge, init cursor past it
__global__ void add_bscan_kernel(int* __restrict__ offs, const int* __restrict__ bscan,
                                 int* __restrict__ cursor, int* __restrict__ csr) {
    int i = blockIdx.x * blockDim.x + threadIdx.x;
    if (i < NN) {
        int o = offs[i] + bscan[i >> 10];
        offs[i] = o;
        csr[o] = i;        // self edge
        cursor[i] = o + 1;
    }
}

__global__ void fill_kernel(const int* __restrict__ src, const int* __restrict__ dst,
                            int* __restrict__ cursor, int* __restrict__ csr) {
    int i = blockIdx.x * blockDim.x + threadIdx.x;
    int stride = gridDim.x * blockDim.x;
    for (; i < NE; i += stride) {
        int p = atomicAdd(&cursor[dst[i]], 1);
        csr[p] = src[i];
    }
}

// ---------------- weight prep: BN fold + MFMA B-fragment layout (fp16) ----------------
// B-frag for mfma_f32_16x16x32_f16: lane l supplies W[k][n] with n = nt*16 + (l&15),
// k = ks*32 + ((l>>4)*8) + j, j=0..7 contiguous. Linear: (((nt*4+ks)*64 + l)*8 + j).

__device__ __forceinline__ int frag_off(int k, int n) {
    int nt = n >> 4, ks = k >> 5;
    int lane = (((k >> 3) & 3) << 4) | (n & 15);
    int j = k & 7;
    return (((nt * 4 + ks) * 64 + lane) * 8 + j);
}

__global__ void fold_frag_bn_kernel(const float* __restrict__ W1, const float* __restrict__ b1,
                                    const float* __restrict__ gamma, const float* __restrict__ beta,
                                    const float* __restrict__ rm, const float* __restrict__ rv,
                                    __half* __restrict__ Wg, float* __restrict__ b1f) {
    int idx = blockIdx.x * blockDim.x + threadIdx.x;
    if (idx < DIM * DIM) {
        int k = idx >> 7, n = idx & 127;
        float sc = rsqrtf(rv[n] + BN_EPS) * gamma[n];
        Wg[frag_off(k, n)] = __float2half(W1[idx] * sc);
        if (idx < DIM) {
            float s2 = rsqrtf(rv[idx] + BN_EPS) * gamma[idx];
            b1f[idx] = (b1[idx] - rm[idx]) * s2 + beta[idx];
        }
    }
}

__global__ void frag_plain_kernel(const float* __restrict__ W, __half* __restrict__ Wg) {
    int idx = blockIdx.x * blockDim.x + threadIdx.x;
    if (idx < DIM * DIM) {
        int k = idx >> 7, n = idx & 127;
        Wg[frag_off(k, n)] = __float2half(W[idx]);
    }
}

// ---------------- fused GIN layer: pipelined gather + MFMA MLP (+optional pool) ----------------

#define TPAD 136  // half stride: 272B rows -> 16B-aligned ds_read_b128 everywhere

__device__ __forceinline__ void acc_row(const int4& raw, float* a) {
    float2 f;
    f = __half22float2(*reinterpret_cast<const __half2*>(&raw.x)); a[0] += f.x; a[1] += f.y;
    f = __half22float2(*reinterpret_cast<const __half2*>(&raw.y)); a[2] += f.x; a[3] += f.y;
    f = __half22float2(*reinterpret_cast<const __half2*>(&raw.z)); a[4] += f.x; a[5] += f.y;
    f = __half22float2(*reinterpret_cast<const __half2*>(&raw.w)); a[6] += f.x; a[7] += f.y;
}

// One 64x128 = tile[64][128] @ W[128][128] + bias, ELU, per-wave 32 cols.
// A-frag: lane l -> m = l&15, k = ks*32 + (l>>4)*8 + j  (16B ds_read)
// C/D:    lane l -> col = l&15 (+nt*16), row = (l>>4)*4 + reg (+mt*16)
__device__ __forceinline__ void mfma_mlp(__half (*tile)[TPAD], int wave, int lane,
                                         const __half* __restrict__ Wg,
                                         const float* __restrict__ bias,
                                         f32x4 acc[4][2]) {
    const int nl = lane & 15;
    const int kb = lane >> 4;
    float bv0 = bias[(2 * wave) * 16 + nl];
    float bv1 = bias[(2 * wave + 1) * 16 + nl];
#pragma unroll
    for (int mt = 0; mt < 4; ++mt) {
        acc[mt][0] = (f32x4){bv0, bv0, bv0, bv0};
        acc[mt][1] = (f32x4){bv1, bv1, bv1, bv1};
    }
    f16x8 Bf[2][4];
#pragma unroll
    for (int ntl = 0; ntl < 2; ++ntl)
#pragma unroll
        for (int ks = 0; ks < 4; ++ks)
            Bf[ntl][ks] = *reinterpret_cast<const f16x8*>(
                &Wg[(((2 * wave + ntl) * 4 + ks) * 64 + lane) * 8]);
#pragma unroll
    for (int ks = 0; ks < 4; ++ks) {
#pragma unroll
        for (int mt = 0; mt < 4; ++mt) {
            f16x8 Af = *reinterpret_cast<const f16x8*>(&tile[mt * 16 + nl][ks * 32 + kb * 8]);
            acc[mt][0] = __builtin_amdgcn_mfma_f32_16x16x32_f16(Af, Bf[0][ks], acc[mt][0], 0, 0, 0);
            acc[mt][1] = __builtin_amdgcn_mfma_f32_16x16x32_f16(Af, Bf[1][ks], acc[mt][1], 0, 0, 0);
        }
    }
}

__device__ __forceinline__ void elu_store(__half (*tile)[TPAD], int wave, int lane,
                                          f32x4 acc[4][2]) {
    const int nl = lane & 15;
    const int rb = (lane >> 4) * 4;
#pragma unroll
    for (int mt = 0; mt < 4; ++mt)
#pragma unroll
        for (int ntl = 0; ntl < 2; ++ntl) {
            int col = (2 * wave + ntl) * 16 + nl;
#pragma unroll
            for (int r = 0; r < 4; ++r)
                tile[mt * 16 + rb + r][col] = __float2half(elu_f(acc[mt][ntl][r]));
        }
}

template <int POOL>
__global__ __launch_bounds__(256) void gin_layer_kernel(
    const __half* __restrict__ fin, const int* __restrict__ offs, const int* __restrict__ csr,
    const __half* __restrict__ Wg1, const float* __restrict__ b1f,
    const __half* __restrict__ Wg2, const float* __restrict__ b2,
    __half* __restrict__ hout, unsigned int* __restrict__ gkey, const int* __restrict__ batch) {
    __shared__ __half accT[64][TPAD];  // 17.4 KB
    __shared__ int batch_s[64];

    const int base = blockIdx.x * 64;
    const int t = threadIdx.x;
    const int lane = t & 63;
    const int wave = t >> 6;

    if (POOL && t < 64) batch_s[t] = batch[base + t];

    const char* finb = reinterpret_cast<const char*>(fin);
    const int g = lane >> 4;            // group 0..3: one node's walk per group
    const int sub = lane & 15;          // 16 B slice within the 256 B feature row
    const size_t boff = (size_t)sub << 4;
    const int k7 = lane & 7;
    const int gl = lane & 48;           // group's base lane for shfl

    // ---- aggregation: 4 nodes per wave concurrently, 8 wide-gathers in flight ----
    for (int q = 0; q < 4; ++q) {
        const int n = base + wave * 16 + q * 4 + g;
        const int e0 = offs[n];
        const int len = offs[n + 1] - e0;            // multiple of 8, >= 8 (incl. self)
        int ml = len;
        ml = max(ml, __shfl_xor(ml, 16));
        ml = max(ml, __shfl_xor(ml, 32));

        float a[8];
#pragma unroll
        for (int k = 0; k < 8; ++k) a[k] = 0.f;

        int idxv = (k7 < len) ? csr[e0 + k7] : NN;

        for (int kb = 0; kb < ml; kb += 8) {
            int idxn = NN;
            int p = kb + 8 + k7;
            if (kb + 8 < ml) idxn = (p < len) ? csr[e0 + p] : NN;

            int s0 = __shfl(idxv, gl + 0);
            int s1 = __shfl(idxv, gl + 1);
            int s2 = __shfl(idxv, gl + 2);
            int s3 = __shfl(idxv, gl + 3);
            int s4 = __shfl(idxv, gl + 4);
            int s5 = __shfl(idxv, gl + 5);
            int s6 = __shfl(idxv, gl + 6);
            int s7 = __shfl(idxv, gl + 7);
            int4 r0 = *reinterpret_cast<const int4*>(finb + ((size_t)s0 << 8) + boff);
            int4 r1 = *reinterpret_cast<const int4*>(finb + ((size_t)s1 << 8) + boff);
            int4 r2 = *reinterpret_cast<const int4*>(finb + ((size_t)s2 << 8) + boff);
            int4 r3 = *reinterpret_cast<const int4*>(finb + ((size_t)s3 << 8) + boff);
            int4 r4 = *reinterpret_cast<const int4*>(finb + ((size_t)s4 << 8) + boff);
            int4 r5 = *reinterpret_cast<const int4*>(finb + ((size_t)s5 << 8) + boff);
            int4 r6 = *reinterpret_cast<const int4*>(finb + ((size_t)s6 << 8) + boff);
            int4 r7 = *reinterpret_cast<const int4*>(finb + ((size_t)s7 << 8) + boff);
            acc_row(r0, a);
            acc_row(r1, a);
            acc_row(r2, a);
            acc_row(r3, a);
            acc_row(r4, a);
            acc_row(r5, a);
            acc_row(r6, a);
            acc_row(r7, a);
            idxv = idxn;
        }

        const int row = wave * 16 + q * 4 + g;
        const int c = sub * 8;
        float2 f;
        f.x = a[0]; f.y = a[1]; *reinterpret_cast<__half2*>(&accT[row][c + 0]) = __float22half2_rn(f);
        f.x = a[2]; f.y = a[3]; *reinterpret_cast<__half2*>(&accT[row][c + 2]) = __float22half2_rn(f);
        f.x = a[4]; f.y = a[5]; *reinterpret_cast<__half2*>(&accT[row][c + 4]) = __float22half2_rn(f);
        f.x = a[6]; f.y = a[7]; *reinterpret_cast<__half2*>(&accT[row][c + 6]) = __float22half2_rn(f);
    }
    __syncthreads();

    f32x4 acc[4][2];

    // ---- GEMM1 (BN folded) + ELU via MFMA ----
    mfma_mlp(accT, wave, lane, Wg1, b1f, acc);
    __syncthreads();  // all A-frag reads done
    elu_store(accT, wave, lane, acc);
    __syncthreads();

    // ---- GEMM2 + ELU via MFMA ----
    mfma_mlp(accT, wave, lane, Wg2, b2, acc);
    __syncthreads();
    elu_store(accT, wave, lane, acc);
    __syncthreads();

    if (!POOL) {
        __half2* hout2 = reinterpret_cast<__half2*>(hout);
        for (int idx = t; idx < 64 * 64; idx += 256) {
            int n = idx >> 6, c2 = idx & 63;
            hout2[(size_t)(base + n) * 64 + c2] =
                *reinterpret_cast<const __half2*>(&accT[n][2 * c2]);
        }
    } else {
        if (t < DIM) {
            const int col = t;
            const int g0 = batch_s[0], g1 = batch_s[63];
            for (int gg = g0; gg <= g1; ++gg) {
                float m = -INFINITY;
                bool any = false;
                for (int i = 0; i < 64; ++i) {
                    if (batch_s[i] == gg) { m = fmaxf(m, __half2float(accT[i][col])); any = true; }
                }
                if (any) atomicMax(&gkey[(size_t)gg * DIM + col], enc_f(m));
            }
        }
    }
}

// ---------------- head ----------------

__global__ __launch_bounds__(128) void head_kernel(const unsigned int* __restrict__ gkey,
                                                   const float* __restrict__ l1W,
                                                   const float* __restrict__ l1b,
                                                   const float* __restrict__ l2W,
                                                   const float* __restrict__ l2b,
                                                   float* __restrict__ out) {
    __shared__ float gv[DIM];
    __shared__ float y1[DIM];
    __shared__ float lg[NC];
    const int g = blockIdx.x;
    const int t = threadIdx.x;
    gv[t] = dec_f(gkey[(size_t)g * DIM + t]);
    __syncthreads();
    float s = l1b[t];
    for (int k = 0; k < DIM; ++k) s += gv[k] * l1W[k * DIM + t];
    y1[t] = elu_f(s);
    __syncthreads();
    if (t < NC) {
        float s2 = l2b[t];
        for (int k = 0; k < DIM; ++k) s2 += y1[k] * l2W[k * NC + t];
        lg[t] = s2;
    }
    __syncthreads();
    if (t == 0) {
        float m = -INFINITY;
        for (int j = 0; j < NC; ++j) m = fmaxf(m, lg[j]);
        float e[NC];
        float sum = 0.f;
        for (int j = 0; j < NC; ++j) { e[j] = expf(lg[j] - m); sum += e[j]; }
        float inv = 1.f / sum;
        for (int j = 0; j < NC; ++j) out[(size_t)g * NC + j] = e[j] * inv;
    }
}

// ---------------- launch ----------------

extern "C" void kernel_launch(void* const* d_in, const int* in_sizes, int n_in,
                              void* d_out, int out_size, void* d_ws, size_t ws_size,
                              hipStream_t stream) {
    (void)in_sizes; (void)n_in; (void)out_size; (void)ws_size;
    const float* x     = (const float*)d_in[0];
    const int*   edge  = (const int*)d_in[1];
    const int*   batch = (const int*)d_in[2];
    const float* c1_W1 = (const float*)d_in[3];
    const float* c1_b1 = (const float*)d_in[4];
    const float* c1_g  = (const float*)d_in[5];
    const float* c1_be = (const float*)d_in[6];
    const float* c1_rm = (const float*)d_in[7];
    const float* c1_rv = (const float*)d_in[8];
    const float* c1_W2 = (const float*)d_in[9];
    const float* c1_b2 = (const float*)d_in[10];
    const float* c2_W1 = (const float*)d_in[11];
    const float* c2_b1 = (const float*)d_in[12];
    const float* c2_g  = (const float*)d_in[13];
    const float* c2_be = (const float*)d_in[14];
    const float* c2_rm = (const float*)d_in[15];
    const float* c2_rv = (const float*)d_in[16];
    const float* c2_W2 = (const float*)d_in[17];
    const float* c2_b2 = (const float*)d_in[18];
    const float* l1_W  = (const float*)d_in[19];
    const float* l1_b  = (const float*)d_in[20];
    const float* l2_W  = (const float*)d_in[21];
    const float* l2_b  = (const float*)d_in[22];
    float* out = (float*)d_out;

    char* wsb = (char*)d_ws;
    size_t off = 0;
    auto take = [&](size_t bytes) -> char* {
        char* p = wsb + off;
        off += (bytes + 255) & ~(size_t)255;
        return p;
    };
    int* counts    = (int*)take((size_t)NN * 4);
    int* offs      = (int*)take((size_t)(NN + 1) * 4);
    int* cursor    = (int*)take((size_t)NN * 4);
    int* bsum      = (int*)take(1024 * 4);
    int* bscan     = (int*)take(1024 * 4);
    int* csr       = (int*)take((size_t)NE_PAD * 4);
    __half* xh     = (__half*)take((size_t)(NN + 1) * DIM * 2);   // +1: zero pad row
    __half* h1h    = (__half*)take((size_t)(NN + 1) * DIM * 2);
    unsigned* gkey = (unsigned*)take((size_t)NG * DIM * 4);
    __half* Wg1_a  = (__half*)take((size_t)DIM * DIM * 2);
    __half* Wg2_a  = (__half*)take((size_t)DIM * DIM * 2);
    __half* Wg1_b  = (__half*)take((size_t)DIM * DIM * 2);
    __half* Wg2_b  = (__half*)take((size_t)DIM * DIM * 2);
    float* b1f_a   = (float*)take((size_t)DIM * 4);
    float* b1f_b   = (float*)take((size_t)DIM * 4);

    const int* esrc = edge;
    const int* edst = edge + NE;

    hipMemsetAsync(counts, 0, (size_t)NN * 4, stream);
    hipMemsetAsync(gkey, 0, (size_t)NG * DIM * 4, stream);
    hipMemsetAsync(xh + (size_t)NN * DIM, 0, DIM * 2, stream);
    hipMemsetAsync(h1h + (size_t)NN * DIM, 0, DIM * 2, stream);

    fold_frag_bn_kernel<<<64, 256, 0, stream>>>(c1_W1, c1_b1, c1_g, c1_be, c1_rm, c1_rv,
                                                Wg1_a, b1f_a);
    frag_plain_kernel<<<64, 256, 0, stream>>>(c1_W2, Wg2_a);
    fold_frag_bn_kernel<<<64, 256, 0, stream>>>(c2_W1, c2_b1, c2_g, c2_be, c2_rm, c2_rv,
                                                Wg1_b, b1f_b);
    frag_plain_kernel<<<64, 256, 0, stream>>>(c2_W2, Wg2_b);

    to_half_kernel<<<2048, 256, 0, stream>>>(x, xh, NN * DIM / 2);

    hist_kernel<<<4096, 256, 0, stream>>>(edst, counts);
    scan_block_kernel<<<196, 1024, 0, stream>>>(counts, offs, bsum);
    scan_bsum_kernel<<<1, 1024, 0, stream>>>(bsum, bscan, 196, offs);
    csr_init_kernel<<<4096, 256, 0, stream>>>(csr);
    add_bscan_kernel<<<782, 256, 0, stream>>>(offs, bscan, cursor, csr);
    fill_kernel<<<4096, 256, 0, stream>>>(esrc, edst, cursor, csr);

    gin_layer_kernel<0><<<NN / 64, 256, 0, stream>>>(xh, offs, csr, Wg1_a, b1f_a, Wg2_a, c1_b2,
                                                     h1h, nullptr, nullptr);
    gin_layer_kernel<1><<<NN / 64, 256, 0, stream>>>(h1h, offs, csr, Wg1_b, b1f_b, Wg2_b, c2_b2,
                                                     nullptr, gkey, batch);

    head_kernel<<<NG, 128, 0, stream>>>(gkey, l1_W, l1_b, l2_W, l2_b, out);
}